// Round 12
// baseline (4307.417 us; speedup 1.0000x reference)
//
#include <hip/hip_runtime.h>

#define KP   2176
#define H    2048
#define IN   69
#define TGT  50
#define NKT  68     // K-tiles of 32 (2048 h + 69 x + pad)

typedef unsigned short ushort_t;
typedef unsigned int   uint_t;
typedef __attribute__((ext_vector_type(8))) short  short8;
typedef __attribute__((ext_vector_type(4))) float  float4_t;

#define MFMA_BF16 __builtin_amdgcn_mfma_f32_16x16x32_bf16

__device__ __forceinline__ ushort_t f2bf(float f) {
  union { float f; unsigned u; } v; v.f = f;
  unsigned u = v.u;
  return (ushort_t)((u + 0x7fffu + ((u >> 16) & 1u)) >> 16);
}

template <int N> __device__ __forceinline__ void waitv() {
  asm volatile("s_waitcnt vmcnt(%0)" :: "n"(N) : "memory");
}
#define LGKM0() asm volatile("s_waitcnt lgkmcnt(0)" ::: "memory")
#define SGB0()  __builtin_amdgcn_sched_barrier(0)
#define FENCE() asm volatile("" ::: "memory")

// normal cached load (W3/F2: read-only, L2-resident across the whole kernel)
template <int OFF> __device__ __forceinline__ void gld(short8& d, uint_t voff, const void* base) {
  asm volatile("global_load_dwordx4 %0, %1, %2 offset:%3"
               : "=v"(d) : "v"(voff), "s"(base), "n"(OFF));
}
// sc0 sc1 = MALL-coherent, no L2 allocation: for everything written during the kernel
template <int OFF> __device__ __forceinline__ void gld_sc(short8& d, uint_t voff, const void* base) {
  asm volatile("global_load_dwordx4 %0, %1, %2 offset:%3 sc0 sc1"
               : "=v"(d) : "v"(voff), "s"(base), "n"(OFF));
}
__device__ __forceinline__ void st128_sc(void* addr, short8 v) {
  asm volatile("global_store_dwordx4 %0, %1, off sc0 sc1" :: "v"(addr), "v"(v) : "memory");
}
__device__ __forceinline__ void st16_sc(void* addr, uint_t v) {
  asm volatile("global_store_short %0, %1, off sc0 sc1" :: "v"(addr), "v"(v) : "memory");
}
__device__ __forceinline__ void st32_sc(void* addr, float v) {
  asm volatile("global_store_dword %0, %1, off sc0 sc1" :: "v"(addr), "v"(v) : "memory");
}
__device__ __forceinline__ void ld32_sc_nw(float& d, const void* addr) {
  asm volatile("global_load_dword %0, %1, off sc0 sc1" : "=v"(d) : "v"(addr) : "memory");
}

// ================= fragment-major layouts (r7/r10-proven) =================
__global__ void build_w3(const float* __restrict__ Whh, const float* __restrict__ Wih,
                         ushort_t* __restrict__ W3) {
  int i = blockIdx.x * 256 + threadIdx.x;   // 384*68*64
  int lane = i & 63;
  int kt = (i >> 6) % NKT;
  int rb = i / (64 * NKT);
  int cb = rb / 3, g = rb - cb * 3;
  int c  = cb * 16 + (lane & 15);
  int gr = g * H + c;
  int k0 = kt * 32 + (lane >> 4) * 8;
  short8 v;
  #pragma unroll
  for (int j = 0; j < 8; ++j) {
    int k = k0 + j;
    float val = 0.f;
    if (k < H) val = Whh[(size_t)gr * H + k];
    else if (k < H + IN) val = Wih[(size_t)gr * IN + (k - H)];
    v[j] = (short)f2bf(val);
  }
  *(short8*)(W3 + (size_t)i * 8) = v;
}

__global__ void build_f2(const float* __restrict__ fc1w, ushort_t* __restrict__ F2) {
  int i = blockIdx.x * 256 + threadIdx.x;   // 64*5*64
  int lane = i & 63;
  int ni = (i >> 6) % 5;
  int kt = i / 320;
  int j  = ni * 16 + (lane & 15);
  int k0 = kt * 32 + (lane >> 4) * 8;
  short8 v;
  #pragma unroll
  for (int jj = 0; jj < 8; ++jj) {
    float val = (j < IN) ? fc1w[(size_t)j * H + k0 + jj] : 0.f;
    v[jj] = (short)f2bf(val);
  }
  *(short8*)(F2 + (size_t)i * 8) = v;
}

__global__ void zero_u4(uint4* p, int n) {
  int i = blockIdx.x * 256 + threadIdx.x;
  if (i < n) p[i] = make_uint4(0, 0, 0, 0);
}

__device__ __forceinline__ size_t a2_x_off(int b, int j) {
  int k = 2048 + j;
  int kt = k >> 5, kk = k & 31;
  int mb = b >> 4;
  int ln = (b & 15) | ((kk >> 3) << 4);
  return ((size_t)(mb * NKT + kt) * 64 + ln) * 16 + (kk & 7) * 2;
}

__global__ void fill_x0(const float* __restrict__ enc, char* __restrict__ A2) {
  int i = blockIdx.x * 256 + threadIdx.x;   // 512*69
  int b = i / IN, j = i - b * IN;
  *(ushort_t*)(A2 + a2_x_off(b, j)) = f2bf(enc[(size_t)b * 100 * IN + j]);
}

// ================= the persistent kernel =================
// grid 256 (1 WG/CU). WG: cg = (bid&7)*4+((bid>>3)&3) (0..31, 64 cols), mt = bid>>5.
// Wave w: cb = cg*4+w (16 cols x 3 gates; B via NORMAL loads -> per-XCD 3.34MB W-slice
// L2-resident across all 149 steps — the whole point of persistence). A (h|x) is
// written every step -> ALL A traffic is sc0 sc1 (MALL-coherent, no L2 alloc, no
// staleness). Exact-issue/exact-drain pipeline per r10 (4 loads/tile/wave).
__global__ __launch_bounds__(256, 1) void persist(
    const char* __restrict__ W3p, char* A0, char* A1, const char* __restrict__ F2p,
    const float* __restrict__ enc, const float* __restrict__ dec,
    const float* __restrict__ bih, const float* __restrict__ bhh,
    const float* __restrict__ fc1b, float* __restrict__ out, int* barcnt)
{
  __shared__ __align__(16) char ldsraw[25600];
  short8  (*Aring)[4][64] = (short8 (*)[4][64])ldsraw;         // 16KB relay ring
  ushort_t (*smh)[72]     = (ushort_t (*)[72])(ldsraw + 16384); // 9.2KB transpose

  const int tid = threadIdx.x;
  const int bid = blockIdx.x;
  const int lane = tid & 63, w = tid >> 6;
  const int l15 = lane & 15, l4 = lane >> 4;
  const int cg = (bid & 7) * 4 + ((bid >> 3) & 3);
  const int mt = bid >> 5;
  const int cb = cg * 4 + w;
  const int c  = cb * 16 + l15;

  const float br  = bih[c] + bhh[c];
  const float bz  = bih[H + c] + bhh[H + c];
  const float bin = bih[2 * H + c];
  const float bhn = bhh[2 * H + c];
  asm volatile("" :: "v"(br), "v"(bz), "v"(bin), "v"(bhn));

  float hreg[4][4] = {};   // persistent fp32 h carry (m = mt*64 + mi*16 + l4*4 + r4)

  const uint_t vAi  = (uint_t)(w * (NKT * 1024) + lane * 16);
  const uint_t vB0i = (uint_t)((cb * 3 + 0) * (NKT * 1024) + lane * 16);
  const uint_t vB1i = vB0i + (uint_t)(NKT * 1024);
  const uint_t vB2i = vB1i + (uint_t)(NKT * 1024);

  int epoch = 0;
  auto gbar = [&]() {
    asm volatile("s_waitcnt vmcnt(0) lgkmcnt(0)" ::: "memory");
    __builtin_amdgcn_s_barrier();
    ++epoch;
    if (tid == 0) {
      atomicAdd(barcnt, 1);               // device-scope (MALL-serialized)
      const int tgt = epoch * 256;
      int v = 0;
      for (int it = 0; it < 20000000; ++it) {
        asm volatile("global_load_dword %0, %1, off sc0 sc1\n\ts_waitcnt vmcnt(0)"
                     : "=v"(v) : "v"((const int*)barcnt) : "memory");
        if (v >= tgt) break;
        __builtin_amdgcn_s_sleep(2);
      }
    }
    __builtin_amdgcn_s_barrier();
  };

  #pragma unroll 1
  for (int t = 0; t < 149; ++t) {
    char* Ain  = (t & 1) ? A1 : A0;
    char* Aout = (t & 1) ? A0 : A1;
    const void* ApW = Ain + (size_t)(mt * 4) * (NKT * 1024);

    uint_t vA = vAi;
    uint_t vB0 = vB0i, vB1 = vB1i, vB2 = vB2i;

    short8 sa[4], fb[8][3];
    short8 fa0, fa1, fa2, fa3;
    float4_t acc[4][4] = {};   // [mi][r, z, gh_n, gi_n]

#define AISS(sl) { gld_sc<0>(sa[sl], vA, ApW); vA += 1024; }
#define BISS(sl) { gld<0>(fb[sl][0], vB0, W3p); gld<0>(fb[sl][1], vB1, W3p); \
                   gld<0>(fb[sl][2], vB2, W3p); vB0 += 1024; vB1 += 1024; vB2 += 1024; }
#define MFMA3(mi, fav, j, G2) \
  acc[mi][0]  = MFMA_BF16(fav, fb[j][0], acc[mi][0], 0, 0, 0); \
  acc[mi][1]  = MFMA_BF16(fav, fb[j][1], acc[mi][1], 0, 0, 0); \
  acc[mi][G2] = MFMA_BF16(fav, fb[j][2], acc[mi][G2], 0, 0, 0);
#define MFMA12(j, G2) MFMA3(0, fa0, j, G2) MFMA3(1, fa1, j, G2) \
                      MFMA3(2, fa2, j, G2) MFMA3(3, fa3, j, G2)
#define RDFA(ss) \
  FENCE(); \
  fa0 = Aring[ss][0][lane]; fa1 = Aring[ss][1][lane]; \
  fa2 = Aring[ss][2][lane]; fa3 = Aring[ss][3][lane];
#define GRUT(u, G2) \
  AISS((u + 4) & 3) BISS((u + 7) & 7) \
  waitv<15>(); SGB0(); \
  Aring[(u + 1) & 3][w][lane] = sa[(u + 1) & 3]; \
  LGKM0(); \
  __builtin_amdgcn_s_barrier(); \
  RDFA(u & 3) \
  LGKM0(); SGB0(); \
  MFMA12(u, G2)
#define GRUTA(u, NW) \
  AISS((u + 4) & 3) \
  waitv<NW>(); SGB0(); \
  Aring[(u + 1) & 3][w][lane] = sa[(u + 1) & 3]; \
  LGKM0(); \
  __builtin_amdgcn_s_barrier(); \
  RDFA(u & 3) \
  LGKM0(); SGB0(); \
  MFMA12(u, 2)
#define GRUTN_W(u, NW, G2) \
  waitv<NW>(); SGB0(); \
  Aring[(u + 1) & 3][w][lane] = sa[(u + 1) & 3]; \
  LGKM0(); \
  __builtin_amdgcn_s_barrier(); \
  RDFA(u & 3) \
  LGKM0(); SGB0(); \
  MFMA12(u, G2)
#define GRUTN_NW(u, NW, G2) \
  waitv<NW>(); SGB0(); \
  LGKM0(); \
  __builtin_amdgcn_s_barrier(); \
  RDFA(u & 3) \
  LGKM0(); SGB0(); \
  MFMA12(u, G2)

    // prologue: A0..A3 + B0..B6 (25 loads); queue was empty (gbar drained to 0)
    AISS(0) AISS(1) AISS(2) AISS(3)
    BISS(0) BISS(1) BISS(2) BISS(3) BISS(4) BISS(5) BISS(6)
    waitv<24>(); SGB0();                 // retire exactly A0
    Aring[0][w][lane] = sa[0];
    LGKM0();
    __builtin_amdgcn_s_barrier();

    #pragma unroll 1
    for (int g8 = 0; g8 < 7; ++g8) {     // tiles 0..55
      GRUT(0, 2) GRUT(1, 2) GRUT(2, 2) GRUT(3, 2)
      GRUT(4, 2) GRUT(5, 2) GRUT(6, 2) GRUT(7, 2)
    }
    // tiles 56..60 (full issues: A60..64, B63..67)
    GRUT(0, 2) GRUT(1, 2) GRUT(2, 2) GRUT(3, 2) GRUT(4, 2)
    // tiles 61..63 (A65..67 issues only; descending exact waits)
    GRUTA(5, 12) GRUTA(6, 9) GRUTA(7, 6)
    // tiles 64..67: x-part -> gi_n; drain exactly to 0
    GRUTN_W(0, 2, 3) GRUTN_W(1, 1, 3) GRUTN_W(2, 0, 3) GRUTN_NW(3, 0, 3)
    // vmcnt == 0, lgkm == 0: nothing outstanding into register reuse below.

    // ---- epilogue: gates fp32, REGISTER carry; h' -> LDS transpose -> 16B sc stores
    #pragma unroll
    for (int mi = 0; mi < 4; ++mi) {
      #pragma unroll
      for (int r4 = 0; r4 < 4; ++r4) {
        float rg = 1.f / (1.f + __expf(-(acc[mi][0][r4] + br)));
        float zg = 1.f / (1.f + __expf(-(acc[mi][1][r4] + bz)));
        float ng = tanhf(acc[mi][3][r4] + bin + rg * (acc[mi][2][r4] + bhn));
        float hn = (1.f - zg) * ng + zg * hreg[mi][r4];
        hreg[mi][r4] = hn;
        smh[mi * 16 + l4 * 4 + r4][w * 16 + l15] = f2bf(hn);
      }
    }
    __syncthreads();
    #pragma unroll
    for (int e = 0; e < 2; ++e) {
      int cid = tid * 2 + e;               // (m 0..63) x (ktrel 0..1) x (khi 0..3)
      int m = cid >> 3, ktrel = (cid >> 2) & 1, khi = cid & 3;
      short8 v = *(const short8*)&smh[m][ktrel * 32 + khi * 8];
      int m_abs = mt * 64 + m;
      int mb2 = m_abs >> 4;
      int ln = (m_abs & 15) | (khi << 4);
      int kt = cg * 2 + ktrel;
      st128_sc(Aout + ((size_t)(mb2 * NKT + kt) * 64 + ln) * 16, v);
    }
    // encoder x-feed (cg==0 WGs: mt 0..7 cover all 512 rows)
    if ((bid & 31) == 0 && t < 99) {
      const float* xs = (t < 98) ? (enc + (size_t)(t + 1) * IN) : dec;
      const int xstride = (t < 98) ? 100 * IN : TGT * IN;
      for (int i = tid; i < 64 * IN; i += 256) {
        int rr = i / IN, cc = i - rr * IN;
        int m = mt * 64 + rr;
        st16_sc(Aout + a2_x_off(m, cc), (uint_t)f2bf(xs[(size_t)m * xstride + cc]));
      }
    }
    gbar();

    // ---- decoder output phase ----
    if (t >= 99) {
      if (bid < 32) {
        const int d = t - 99;
        const int mbo = bid;
        float4_t* redf = (float4_t*)ldsraw;   // 20KB overlay (gru LDS dead here)
        const void* F2b = (const char*)F2p + 4096;
        uint_t voA = (uint_t)((mbo * NKT + w * 16) * 1024 + lane * 16);
        uint_t vf  = (uint_t)((w * 16) * 5120 + lane * 16);
        short8 da[8], db[8][5];
        float4_t oa[5] = {};

#define DPRO(sl) \
        gld_sc<0>(da[sl], voA, Aout); \
        gld<0>(db[sl][0], vf, F2p); gld<1024>(db[sl][1], vf, F2p); \
        gld<2048>(db[sl][2], vf, F2p); gld<3072>(db[sl][3], vf, F2p); \
        gld<0>(db[sl][4], vf, F2b); \
        voA += 1024; vf += 5120;
#define DMM(sl) \
        { _Pragma("unroll") for (int nf = 0; nf < 5; ++nf) \
            oa[nf] = MFMA_BF16(da[sl], db[sl][nf], oa[nf], 0, 0, 0); }

        DPRO(0) DPRO(1) DPRO(2) DPRO(3) DPRO(4) DPRO(5) DPRO(6) DPRO(7)
        waitv<42>(); SGB0(); DMM(0) DPRO(0)
        waitv<42>(); SGB0(); DMM(1) DPRO(1)
        waitv<42>(); SGB0(); DMM(2) DPRO(2)
        waitv<42>(); SGB0(); DMM(3) DPRO(3)
        waitv<42>(); SGB0(); DMM(4) DPRO(4)
        waitv<42>(); SGB0(); DMM(5) DPRO(5)
        waitv<42>(); SGB0(); DMM(6) DPRO(6)
        waitv<42>(); SGB0(); DMM(7) DPRO(7)
        waitv<42>(); SGB0(); DMM(0)
        waitv<36>(); SGB0(); DMM(1)
        waitv<30>(); SGB0(); DMM(2)
        waitv<24>(); SGB0(); DMM(3)
        waitv<18>(); SGB0(); DMM(4)
        waitv<12>(); SGB0(); DMM(5)
        waitv<6>();  SGB0(); DMM(6)
        waitv<0>();  SGB0(); DMM(7)
        // drained to 0.

        #pragma unroll
        for (int nf = 0; nf < 5; ++nf) redf[(w * 5 + nf) * 64 + lane] = oa[nf];
        __syncthreads();

        #pragma unroll 1
        for (int pass = 0; pass < 2; ++pass) {
          if (pass == 1 && w != 0) break;
          const int nf = pass ? 4 : w;
          float4_t sum = redf[(0 * 5 + nf) * 64 + lane] + redf[(1 * 5 + nf) * 64 + lane]
                       + redf[(2 * 5 + nf) * 64 + lane] + redf[(3 * 5 + nf) * 64 + lane];
          int j = nf * 16 + l15;
          if (j < IN) {
            float bj = fc1b[j];
            float iv0, iv1, iv2, iv3;
            if (d == 0) {
              iv0 = dec[(size_t)(mbo * 16 + l4 * 4 + 0) * (TGT * IN) + j];
              iv1 = dec[(size_t)(mbo * 16 + l4 * 4 + 1) * (TGT * IN) + j];
              iv2 = dec[(size_t)(mbo * 16 + l4 * 4 + 2) * (TGT * IN) + j];
              iv3 = dec[(size_t)(mbo * 16 + l4 * 4 + 3) * (TGT * IN) + j];
            } else {
              const float* pv = out + (size_t)(d - 1) * IN + j;
              ld32_sc_nw(iv0, pv + (size_t)(mbo * 16 + l4 * 4 + 0) * (TGT * IN));
              ld32_sc_nw(iv1, pv + (size_t)(mbo * 16 + l4 * 4 + 1) * (TGT * IN));
              ld32_sc_nw(iv2, pv + (size_t)(mbo * 16 + l4 * 4 + 2) * (TGT * IN));
              ld32_sc_nw(iv3, pv + (size_t)(mbo * 16 + l4 * 4 + 3) * (TGT * IN));
              waitv<0>(); SGB0();
            }
            float ivv[4] = {iv0, iv1, iv2, iv3};
            #pragma unroll
            for (int r4 = 0; r4 < 4; ++r4) {
              int m = mbo * 16 + l4 * 4 + r4;
              float v = sum[r4] + bj + ivv[r4];
              st32_sc(out + (size_t)m * (TGT * IN) + (size_t)d * IN + j, v);
              st16_sc(Aout + a2_x_off(m, j), (uint_t)f2bf(v));   // next decoder input
            }
          }
        }
      }
      gbar();
    }
  }
}

// ================= launch =================
extern "C" void kernel_launch(void* const* d_in, const int* in_sizes, int n_in,
                              void* d_out, int out_size, void* d_ws, size_t ws_size,
                              hipStream_t stream) {
  const float* enc  = (const float*)d_in[0];
  const float* dec  = (const float*)d_in[1];
  const float* Wih  = (const float*)d_in[2];
  const float* Whh  = (const float*)d_in[3];
  const float* b_ih = (const float*)d_in[4];
  const float* b_hh = (const float*)d_in[5];
  const float* fc1w = (const float*)d_in[6];
  const float* fc1b = (const float*)d_in[7];
  float* out = (float*)d_out;

  char* ws = (char*)d_ws;
  ushort_t* W3  = (ushort_t*)ws;                    // 26,738,688
  char*     A0  = ws + 26738688;                    // 2,228,224
  char*     A1  = ws + 28966912;                    // 2,228,224
  int*      bar = (int*)(ws + 31195136);            // 1,024
  ushort_t* F2  = (ushort_t*)(ws + 31196160);       // 327,680

  build_w3<<<6528, 256, 0, stream>>>(Whh, Wih, W3);
  zero_u4<<<1089, 256, 0, stream>>>((uint4*)A0, 278592);   // A0 + A1 + bar
  fill_x0<<<138, 256, 0, stream>>>(enc, A0);
  build_f2<<<80, 256, 0, stream>>>(fc1w, F2);

  persist<<<256, 256, 0, stream>>>((const char*)W3, A0, A1, (const char*)F2,
                                   enc, dec, b_ih, b_hh, fc1b, out, bar);
}